// Round 4
// baseline (37.594 us; speedup 1.0000x reference)
//
#include <hip/hip_runtime.h>

#define IGNORE_LABEL 255
#define MIN_KEPT 100000u
#define THRESH 0.7f
#define LOG_THRESH (-0.3566749439387324f)   // ln(0.7)

constexpr int N_PIX = 1 << 21;                 // 2*16*256*256 pixels (b,d,h,w)
constexpr int C = 16;                          // channels
constexpr int CH_STRIDE = 1 << 20;             // d*h*w
constexpr int B_STRIDE = C * CH_STRIDE;
constexpr int NBLK = 2048;                     // 2048 blk * 256 thr * 4 pix = N_PIX

typedef float f32x4 __attribute__((ext_vector_type(4)));
typedef int   i32x4 __attribute__((ext_vector_type(4)));

// ---------------------------------------------------------------------------
// Fused pass: per-pixel log-softmax; speculative OHEM sums assuming the
// threshold is exactly 0.7 (true iff count >= MIN_KEPT, checked in k_final).
// Log-domain test: p_target <= 0.7  <=>  u = (x_t - m) - lse <= ln(0.7),
// so no exp/rcp for the probability is ever needed; nll = -u.
// Per-block partials written unconditionally -> no atomics, no init, no memset.
// ---------------------------------------------------------------------------
__global__ __launch_bounds__(256) void k_fused(const float* __restrict__ pred,
                                               const int* __restrict__ target,
                                               float* __restrict__ psum,
                                               float* __restrict__ pcnt) {
    int tid = blockIdx.x * 256 + threadIdx.x;
    int n = tid * 4;                           // 4 consecutive pixels
    int b = n >> 20;
    int rem = n & (CH_STRIDE - 1);
    const float* base = pred + b * B_STRIDE + rem;

    i32x4 tg4 = __builtin_nontemporal_load((const i32x4*)(target + n));

    f32x4 x[C];
#pragma unroll
    for (int c = 0; c < C; ++c)
        x[c] = __builtin_nontemporal_load((const f32x4*)(base + c * CH_STRIDE));

    float s = 0.0f, cn = 0.0f;
#pragma unroll
    for (int j = 0; j < 4; ++j) {
        int t = tg4[j];
        bool valid = (t != IGNORE_LABEL);
        int t0 = valid ? t : 0;

        // max over 16 channels (compiler fuses to v_max3 chains)
        float m = fmaxf(fmaxf(fmaxf(x[0][j], x[1][j]), fmaxf(x[2][j], x[3][j])),
                        fmaxf(fmaxf(x[4][j], x[5][j]), fmaxf(x[6][j], x[7][j])));
        float m2 = fmaxf(fmaxf(fmaxf(x[8][j], x[9][j]), fmaxf(x[10][j], x[11][j])),
                         fmaxf(fmaxf(x[12][j], x[13][j]), fmaxf(x[14][j], x[15][j])));
        m = fmaxf(m, m2);

        float se = 0.0f;
        float xt = x[0][j];
#pragma unroll
        for (int c = 0; c < C; ++c) {
            se += __expf(x[c][j] - m);
            if (c == t0) xt = x[c][j];         // compile-time c vs runtime t0 -> cndmask
        }
        float u = (xt - m) - __logf(se);       // log p_target
        bool keep = valid && (u <= LOG_THRESH);
        float k = keep ? 1.0f : 0.0f;
        s += k * (-u);                          // nll = -log p
        cn += k;
    }

    // wave + block reduce (deterministic order)
#pragma unroll
    for (int off = 32; off > 0; off >>= 1) {
        s += __shfl_down(s, off);
        cn += __shfl_down(cn, off);
    }
    __shared__ float ls[4], lc[4];
    int lane = threadIdx.x & 63, w = threadIdx.x >> 6;
    if (lane == 0) { ls[w] = s; lc[w] = cn; }
    __syncthreads();
    if (threadIdx.x == 0) {
        float2 o;
        o.x = ls[0] + ls[1] + ls[2] + ls[3];
        o.y = lc[0] + lc[1] + lc[2] + lc[3];
        psum[blockIdx.x] = o.x;
        pcnt[blockIdx.x] = o.y;
    }
}

// Scalar recompute of masked target-prob + nll for one pixel (slow path only).
__device__ __noinline__ float slow_prob(const float* __restrict__ pred,
                                        const int* __restrict__ target,
                                        int n, float* nll) {
    int b = n >> 20, rem = n & (CH_STRIDE - 1);
    const float* base = pred + b * B_STRIDE + rem;
    int t = target[n];
    bool valid = (t != IGNORE_LABEL);
    int t0 = valid ? t : 0;
    float xs[C], m = -1e30f;
#pragma unroll
    for (int c = 0; c < C; ++c) { xs[c] = base[c * CH_STRIDE]; m = fmaxf(m, xs[c]); }
    float se = 0.0f, xt = xs[0];
#pragma unroll
    for (int c = 0; c < C; ++c) {
        se += __expf(xs[c] - m);
        if (c == t0) xt = xs[c];
    }
    float d = xt - m;
    *nll = __logf(se) - d;
    float p = __expf(d) / se;
    return valid ? p : 1.0f;
}

// ---------------------------------------------------------------------------
// Final: combine partials. Fast path (cnt >= MIN_KEPT): threshold is exactly
// 0.7, speculative sums are the answer. Slow path (never taken for this
// input, kept for correctness): exact 3-level radix select over recomputed
// mask_prob bit patterns, then masked mean.
// ---------------------------------------------------------------------------
__global__ __launch_bounds__(256) void k_final(const float* __restrict__ psum,
                                               const float* __restrict__ pcnt,
                                               const float* __restrict__ pred,
                                               const int* __restrict__ target,
                                               float* __restrict__ out) {
    int tid = threadIdx.x;
    __shared__ double rs[256], rc[256];
    double s = 0.0, c = 0.0;
    for (int i = tid; i < NBLK; i += 256) { s += (double)psum[i]; c += (double)pcnt[i]; }
    rs[tid] = s; rc[tid] = c;
    __syncthreads();
    for (int off = 128; off > 0; off >>= 1) {
        if (tid < off) { rs[tid] += rs[tid + off]; rc[tid] += rc[tid + off]; }
        __syncthreads();
    }
    double tots = rs[0], totc = rc[0];        // uniform across block after sync

    if (totc >= (double)MIN_KEPT) {
        if (tid == 0) out[0] = (float)(tots / (totc < 1.0 ? 1.0 : totc));
        return;                                // uniform exit
    }

    // ---- slow exact path ----
    __shared__ unsigned h[4096];
    __shared__ unsigned s_bin, s_krem;
    float dummy;

    // level 0: bits >> 20
    for (int i = tid; i < 4096; i += 256) h[i] = 0;
    __syncthreads();
    for (int nn = tid; nn < N_PIX; nn += 256) {
        unsigned bits = __float_as_uint(slow_prob(pred, target, nn, &dummy));
        atomicAdd(&h[bits >> 20], 1u);
    }
    __syncthreads();
    if (tid == 0) {
        unsigned run = 0;
        for (unsigned bb = 0; bb < 4096; ++bb) {
            unsigned cv = h[bb];
            if (MIN_KEPT <= run + cv) { s_bin = bb; s_krem = MIN_KEPT - run; break; }
            run += cv;
        }
    }
    __syncthreads();
    unsigned p0 = s_bin, k1 = s_krem;
    __syncthreads();

    // level 1: (bits >> 8) & 0xFFF
    for (int i = tid; i < 4096; i += 256) h[i] = 0;
    __syncthreads();
    for (int nn = tid; nn < N_PIX; nn += 256) {
        unsigned bits = __float_as_uint(slow_prob(pred, target, nn, &dummy));
        if ((bits >> 20) == p0) atomicAdd(&h[(bits >> 8) & 0xFFFu], 1u);
    }
    __syncthreads();
    if (tid == 0) {
        unsigned run = 0;
        for (unsigned bb = 0; bb < 4096; ++bb) {
            unsigned cv = h[bb];
            if (k1 <= run + cv) { s_bin = bb; s_krem = k1 - run; break; }
            run += cv;
        }
    }
    __syncthreads();
    unsigned p1 = (p0 << 12) | s_bin;
    unsigned k2 = s_krem;
    __syncthreads();

    // level 2: bits & 0xFF
    for (int i = tid; i < 256; i += 256) h[i] = 0;
    __syncthreads();
    for (int nn = tid; nn < N_PIX; nn += 256) {
        unsigned bits = __float_as_uint(slow_prob(pred, target, nn, &dummy));
        if ((bits >> 8) == p1) atomicAdd(&h[bits & 0xFFu], 1u);
    }
    __syncthreads();
    if (tid == 0) {
        unsigned run = 0;
        for (unsigned bb = 0; bb < 256; ++bb) {
            unsigned cv = h[bb];
            if (k2 <= run + cv) { s_bin = (p1 << 8) | bb; break; }
            run += cv;
        }
    }
    __syncthreads();
    float thr = fmaxf(THRESH, __uint_as_float(s_bin));

    // masked mean at exact threshold
    double fs = 0.0, fc = 0.0;
    for (int nn = tid; nn < N_PIX; nn += 256) {
        float nll;
        float mp = slow_prob(pred, target, nn, &nll);
        if (target[nn] != IGNORE_LABEL && mp <= thr) { fs += (double)nll; fc += 1.0; }
    }
    __syncthreads();
    rs[tid] = fs; rc[tid] = fc;
    __syncthreads();
    for (int off = 128; off > 0; off >>= 1) {
        if (tid < off) { rs[tid] += rs[tid + off]; rc[tid] += rc[tid + off]; }
        __syncthreads();
    }
    if (tid == 0) {
        double cc = rc[0] < 1.0 ? 1.0 : rc[0];
        out[0] = (float)(rs[0] / cc);
    }
}

extern "C" void kernel_launch(void* const* d_in, const int* in_sizes, int n_in,
                              void* d_out, int out_size, void* d_ws, size_t ws_size,
                              hipStream_t stream) {
    const float* pred = (const float*)d_in[0];
    const int* target = (const int*)d_in[1];
    float* out = (float*)d_out;

    float* psum = (float*)d_ws;                // NBLK floats, written before read
    float* pcnt = psum + NBLK;                 // NBLK floats

    k_fused<<<NBLK, 256, 0, stream>>>(pred, target, psum, pcnt);
    k_final<<<1, 256, 0, stream>>>(psum, pcnt, pred, target, out);
}